// Round 6
// baseline (4580.422 us; speedup 1.0000x reference)
//
#include <hip/hip_runtime.h>

#define CH 32
#define KOFF 27
#define BN_EPS 1e-5f
#define FXS 512.0f
#define FXI (1.0f / 512.0f)

#define BINV 128            // voxels per bin (bin = oi >> 7)
#define NBINS 8192          // allocated bins (max used: (1e6-1)>>7 = 7812)
#define NBK (NBINS * KOFF)  // (bin,k) groups

typedef short bf16x8 __attribute__((ext_vector_type(8)));
typedef float f32x4 __attribute__((ext_vector_type(4)));
typedef unsigned long long u64;
typedef unsigned int u32;

__device__ __forceinline__ unsigned short f2bf(float f) {
    unsigned u = __builtin_bit_cast(unsigned, f);
    u = (u + 0x7fffu + ((u >> 16) & 1u)) >> 16;   // round-to-nearest-even
    return (unsigned short)u;
}

__device__ __forceinline__ void decode4(u64 v, float* f) {
    long long w = (long long)v;
    int s0 = (short)(w & 0xFFFF);          w -= (long long)s0;
    int s1 = (short)((w >> 16) & 0xFFFF);  w -= ((long long)s1 << 16);
    int s2 = (short)((w >> 32) & 0xFFFF);  w -= ((long long)s2 << 32);
    int s3 = (int)(w >> 48);
    f[0] = s0 * FXI; f[1] = s1 * FXI; f[2] = s2 * FXI; f[3] = s3 * FXI;
}

// ===================== rulebook-inversion path =====================

// x f32 -> bf16 rows (64B per voxel)
__global__ __launch_bounds__(256) void xbf_kernel(
    const float* __restrict__ x, uint4* __restrict__ xbf, int n8)
{
    int tid = blockIdx.x * blockDim.x + threadIdx.x;
    int stride = gridDim.x * blockDim.x;
    for (int j = tid; j < n8; j += stride) {
        const f32x4* xp = (const f32x4*)(x + (size_t)j * 8);
        f32x4 v0 = xp[0], v1 = xp[1];
        uint4 o;
        o.x = (u32)f2bf(v0[0]) | ((u32)f2bf(v0[1]) << 16);
        o.y = (u32)f2bf(v0[2]) | ((u32)f2bf(v0[3]) << 16);
        o.z = (u32)f2bf(v1[0]) | ((u32)f2bf(v1[1]) << 16);
        o.w = (u32)f2bf(v1[2]) | ((u32)f2bf(v1[3]) << 16);
        xbf[j] = o;
    }
}

// count per (bin,k)
__global__ __launch_bounds__(256) void hist_kernel(
    const int* __restrict__ out_idx, u32* __restrict__ cnt, int P)
{
    int tid = blockIdx.x * blockDim.x + threadIdx.x;
    int stride = gridDim.x * blockDim.x;
    for (int k = 0; k < KOFF; ++k) {
        const int* op = out_idx + (size_t)k * P;
        for (int j = tid; j < P; j += stride) {
            u32 oi = (u32)op[j];
            atomicAdd(&cnt[(oi >> 7) * KOFF + k], 1u);
        }
    }
}

// per-bin exclusive prefix over k, and bin totals
__global__ __launch_bounds__(256) void binpfx_kernel(
    const u32* __restrict__ cnt, u32* __restrict__ pfx, u32* __restrict__ binTot)
{
    int b = blockIdx.x * blockDim.x + threadIdx.x;
    if (b >= NBINS) return;
    u32 run = 0;
#pragma unroll
    for (int k = 0; k < KOFF; ++k) {
        pfx[b * KOFF + k] = run;
        run += cnt[b * KOFF + k];
    }
    binTot[b] = run;
}

// single-block exclusive scan of NBINS bin totals (256 thr x 32 each)
__global__ __launch_bounds__(256) void scan_kernel(
    const u32* __restrict__ binTot, u32* __restrict__ binStart)
{
    __shared__ u32 wsum[4];
    int t = threadIdx.x;
    u32 loc[32]; u32 s = 0;
#pragma unroll
    for (int i = 0; i < 32; ++i) { loc[i] = binTot[t * 32 + i]; s += loc[i]; }
    u32 incl = s;
#pragma unroll
    for (int off = 1; off < 64; off <<= 1) {
        u32 v = (u32)__shfl_up((int)incl, off);
        if ((t & 63) >= off) incl += v;
    }
    if ((t & 63) == 63) wsum[t >> 6] = incl;
    __syncthreads();
    u32 wb = 0;
    for (int w = 0; w < (t >> 6); ++w) wb += wsum[w];
    u32 run = wb + incl - s;
#pragma unroll
    for (int i = 0; i < 32; ++i) { binStart[t * 32 + i] = run; run += loc[i]; }
}

__global__ __launch_bounds__(256) void initcur_kernel(
    const u32* __restrict__ binStart, const u32* __restrict__ pfx,
    u32* __restrict__ cur)
{
    int i = blockIdx.x * blockDim.x + threadIdx.x;
    if (i < NBK) cur[i] = binStart[i / KOFF] + pfx[i];
}

// invert rulebook: rec[slot] = ii<<7 | (oi & 127), grouped by (bin,k)
__global__ __launch_bounds__(256) void scatter_kernel(
    const int* __restrict__ in_idx, const int* __restrict__ out_idx,
    u32* __restrict__ cur, u32* __restrict__ rec, int P)
{
    int tid = blockIdx.x * blockDim.x + threadIdx.x;
    int stride = gridDim.x * blockDim.x;
    for (int k = 0; k < KOFF; ++k) {
        const int* op = out_idx + (size_t)k * P;
        const int* ip = in_idx + (size_t)k * P;
        for (int j = tid; j < P; j += stride) {
            u32 oi = (u32)op[j];
            u32 ii = (u32)ip[j];
            u32 slot = atomicAdd(&cur[(oi >> 7) * KOFF + k], 1u);
            rec[slot] = (ii << 7) | (oi & 127u);
        }
    }
}

// consumer: block = one bin; coalesced record stream, bf16 gather, MFMA,
// LDS f32 accumulate, fused stats, coalesced y write.
template <bool XBF>
__global__ __launch_bounds__(256) void conv_bin_kernel(
    const uint4* __restrict__ xbf, const float* __restrict__ xf,
    const float* __restrict__ W,
    const u32* __restrict__ rec,
    const u32* __restrict__ binStart, const u32* __restrict__ pfx,
    const u32* __restrict__ cur,          // group ends after scatter
    float* __restrict__ stats, float* __restrict__ y, int N)
{
    __shared__ float accf[BINV * 33];
    __shared__ u32 kofs[KOFF], kend[KOFF];
    __shared__ float ls[CH], ls2[CH];

    const int b   = blockIdx.x;
    const int tid = threadIdx.x;
    const int lane = tid & 63;
    const int wv  = tid >> 6;
    const int r16 = lane & 15;
    const int g   = lane >> 4;

    for (int j = tid; j < BINV * 33; j += 256) accf[j] = 0.f;
    if (tid < KOFF) {
        kofs[tid] = binStart[b] + pfx[b * KOFF + tid];
        kend[tid] = cur[b * KOFF + tid];
    }
    if (tid < CH) { ls[tid] = 0.f; ls2[tid] = 0.f; }
    __syncthreads();

    for (int k = wv; k < KOFF; k += 4) {
        const int s = (int)kofs[k], e = (int)kend[k];
        if (s == e) continue;
        const float* Wk = W + k * CH * CH;
        bf16x8 b0, b1;
#pragma unroll
        for (int j = 0; j < 8; ++j) {
            int kk = g * 8 + j;
            b0[j] = (short)f2bf(Wk[kk * CH + r16]);
            b1[j] = (short)f2bf(Wk[kk * CH + 16 + r16]);
        }
        for (int t = s; t < e; t += 16) {
            int idx = t + r16;
            u32 r = (idx < e) ? rec[idx] : 0u;     // coalesced 64B line
            u32 ii = r >> 7;
            bf16x8 a;
            if (XBF) {
                uint4 raw = xbf[(size_t)ii * 4 + g];
                a = __builtin_bit_cast(bf16x8, raw);
            } else {
                const f32x4* xr = (const f32x4*)(xf + (size_t)ii * CH + g * 8);
                f32x4 x0 = xr[0], x1 = xr[1];
                a[0] = (short)f2bf(x0[0]); a[1] = (short)f2bf(x0[1]);
                a[2] = (short)f2bf(x0[2]); a[3] = (short)f2bf(x0[3]);
                a[4] = (short)f2bf(x1[0]); a[5] = (short)f2bf(x1[1]);
                a[6] = (short)f2bf(x1[2]); a[7] = (short)f2bf(x1[3]);
            }
            f32x4 d0 = {0.f, 0.f, 0.f, 0.f};
            f32x4 d1 = {0.f, 0.f, 0.f, 0.f};
            d0 = __builtin_amdgcn_mfma_f32_16x16x32_bf16(a, b0, d0, 0, 0, 0);
            d1 = __builtin_amdgcn_mfma_f32_16x16x32_bf16(a, b1, d1, 0, 0, 0);

            int vlo = (int)(r & 127u);
#pragma unroll
            for (int i = 0; i < 4; ++i) {
                int src = g * 4 + i;               // record row index in tile
                int v = __shfl(vlo, src);          // its oi low bits
                if (t + src < e) {
                    atomicAdd(&accf[v * 33 + r16], d0[i]);
                    atomicAdd(&accf[v * 33 + 16 + r16], d1[i]);
                }
            }
        }
    }
    __syncthreads();

    // stats partials: 8 row-groups x 32 channels
    {
        int grp = tid >> 5, c = tid & 31;
        float s = 0.f, q = 0.f;
#pragma unroll
        for (int rr = 0; rr < 16; ++rr) {
            float v = accf[(grp * 16 + rr) * 33 + c];
            s += v; q += v * v;
        }
        atomicAdd(&ls[c], s);
        atomicAdd(&ls2[c], q);
    }
    // y write: thread = half-row, fully coalesced
    {
        int row = tid >> 1, half = tid & 1;
        int grow = b * BINV + row;
        if (grow < N) {
            float vals[16];
#pragma unroll
            for (int i = 0; i < 16; ++i) vals[i] = accf[row * 33 + half * 16 + i];
            f32x4* yo = (f32x4*)(y + (size_t)grow * CH + half * 16);
#pragma unroll
            for (int j = 0; j < 4; ++j) {
                f32x4 o = { vals[4*j], vals[4*j+1], vals[4*j+2], vals[4*j+3] };
                yo[j] = o;
            }
        }
    }
    __syncthreads();
    if (tid < CH) {
        atomicAdd(&stats[tid], ls[tid]);
        atomicAdd(&stats[CH + tid], ls2[tid]);
    }
}

__global__ __launch_bounds__(256) void bn_relu_kernel(
    f32x4* __restrict__ y4, const float* __restrict__ stats,
    const float* __restrict__ gamma, const float* __restrict__ beta,
    float invN, int n4)
{
    __shared__ float sc[CH], bi[CH];
    if (threadIdx.x < CH) {
        int c = threadIdx.x;
        float mean = stats[c] * invN;
        float var  = stats[CH + c] * invN - mean * mean;
        float s = gamma[c] * rsqrtf(var + BN_EPS);
        sc[c] = s;
        bi[c] = beta[c] - mean * s;
    }
    __syncthreads();

    int tid = blockIdx.x * blockDim.x + threadIdx.x;
    int stride = gridDim.x * blockDim.x;
    for (int i = tid; i < n4; i += stride) {
        f32x4 v = y4[i];
        int c = (i * 4) & (CH - 1);
        f32x4 o;
        o[0] = fmaxf(v[0] * sc[c + 0] + bi[c + 0], 0.f);
        o[1] = fmaxf(v[1] * sc[c + 1] + bi[c + 1], 0.f);
        o[2] = fmaxf(v[2] * sc[c + 2] + bi[c + 2], 0.f);
        o[3] = fmaxf(v[3] * sc[c + 3] + bi[c + 3], 0.f);
        y4[i] = o;
    }
}

// ===================== R2 fallback path (u64 fixed-point atomics) ============

__global__ __launch_bounds__(256) void conv_fx_kernel(
    const float* __restrict__ x, const float* __restrict__ W,
    const int* __restrict__ in_idx, const int* __restrict__ out_idx,
    u64* __restrict__ yfx, int P, int tilesPerK, int tilesPerWave)
{
    const int k    = blockIdx.y;
    const int lane = threadIdx.x & 63;
    const int wv   = threadIdx.x >> 6;
    const int r16  = lane & 15;
    const int g    = lane >> 4;

    const float* Wk = W + k * CH * CH;
    bf16x8 b0, b1;
#pragma unroll
    for (int j = 0; j < 8; ++j) {
        int kk = g * 8 + j;
        b0[j] = (short)f2bf(Wk[kk * CH + 2 * r16]);
        b1[j] = (short)f2bf(Wk[kk * CH + 2 * r16 + 1]);
    }

    const int kP = k * P;
    int t0 = (blockIdx.x * 4 + wv) * tilesPerWave;
    int t1 = t0 + tilesPerWave;
    if (t1 > tilesPerK) t1 = tilesPerK;

    const int iBase = (r16 & 1) ? 2 : 0;
    const int m     = r16 >> 1;

    for (int t = t0; t < t1; ++t) {
        const int base = t * 16;
        int pi = base + r16;
        if (pi >= P) pi = P - 1;
        const int ii = in_idx[kP + pi];
        const float* xr = x + ii * CH + g * 8;
        f32x4 x0 = *(const f32x4*)xr;
        f32x4 x1 = *(const f32x4*)(xr + 4);
        bf16x8 a;
        a[0] = (short)f2bf(x0[0]); a[1] = (short)f2bf(x0[1]);
        a[2] = (short)f2bf(x0[2]); a[3] = (short)f2bf(x0[3]);
        a[4] = (short)f2bf(x1[0]); a[5] = (short)f2bf(x1[1]);
        a[6] = (short)f2bf(x1[2]); a[7] = (short)f2bf(x1[3]);

        f32x4 d0 = {0.f, 0.f, 0.f, 0.f};
        f32x4 d1 = {0.f, 0.f, 0.f, 0.f};
        d0 = __builtin_amdgcn_mfma_f32_16x16x32_bf16(a, b0, d0, 0, 0, 0);
        d1 = __builtin_amdgcn_mfma_f32_16x16x32_bf16(a, b1, d1, 0, 0, 0);

        unsigned qi[4];
#pragma unroll
        for (int i = 0; i < 4; ++i) {
            int s0 = __float2int_rn(d0[i] * FXS);
            int s1 = __float2int_rn(d1[i] * FXS);
            qi[i] = (unsigned)(s0 & 0xFFFF) | ((unsigned)s1 << 16);
        }
        unsigned pq[4];
#pragma unroll
        for (int i = 0; i < 4; ++i) pq[i] = (unsigned)__shfl_xor((int)qi[i], 1);

#pragma unroll
        for (int s = 0; s < 2; ++s) {
            const int i  = iBase + s;
            const int pr = base + g * 4 + i;
            if (pr < P) {
                const int oi = out_idx[kP + pr];
                int a0 = (short)(qi[i] & 0xFFFF), a1 = (short)(qi[i] >> 16);
                int c0 = (short)(pq[i] & 0xFFFF), c1 = (short)(pq[i] >> 16);
                long long A;
                if (!(r16 & 1))
                    A = (long long)a0 + ((long long)a1 << 16)
                      + ((long long)c0 << 32) + ((long long)c1 << 48);
                else
                    A = (long long)c0 + ((long long)c1 << 16)
                      + ((long long)a0 << 32) + ((long long)a1 << 48);
                atomicAdd(&yfx[(size_t)oi * 8 + m], (u64)A);
            }
        }
    }
}

__global__ __launch_bounds__(256) void stats_fx_kernel(
    const u64* __restrict__ yfx, float* __restrict__ stats, int nW)
{
    __shared__ float ls[CH], ls2[CH];
    if (threadIdx.x < CH) { ls[threadIdx.x] = 0.f; ls2[threadIdx.x] = 0.f; }
    __syncthreads();

    int tid = blockIdx.x * blockDim.x + threadIdx.x;
    int stride = gridDim.x * blockDim.x;
    float s[4] = {0,0,0,0}, q[4] = {0,0,0,0};
    for (int i = tid; i < nW; i += stride) {
        float f[4];
        decode4(yfx[i], f);
#pragma unroll
        for (int j = 0; j < 4; ++j) { s[j] += f[j]; q[j] += f[j] * f[j]; }
    }
    int c = (tid & 7) * 4;
#pragma unroll
    for (int j = 0; j < 4; ++j) {
        atomicAdd(&ls[c + j], s[j]);
        atomicAdd(&ls2[c + j], q[j]);
    }
    __syncthreads();
    if (threadIdx.x < CH) {
        atomicAdd(&stats[threadIdx.x], ls[threadIdx.x]);
        atomicAdd(&stats[CH + threadIdx.x], ls2[threadIdx.x]);
    }
}

__global__ __launch_bounds__(256) void bn_relu_fx_kernel(
    const u64* __restrict__ yfx, f32x4* __restrict__ out4,
    const float* __restrict__ stats,
    const float* __restrict__ gamma, const float* __restrict__ beta,
    float invN, int nW)
{
    __shared__ float sc[CH], bi[CH];
    if (threadIdx.x < CH) {
        int c = threadIdx.x;
        float mean = stats[c] * invN;
        float var  = stats[CH + c] * invN - mean * mean;
        float s = gamma[c] * rsqrtf(var + BN_EPS);
        sc[c] = s;
        bi[c] = beta[c] - mean * s;
    }
    __syncthreads();

    int tid = blockIdx.x * blockDim.x + threadIdx.x;
    int stride = gridDim.x * blockDim.x;
    for (int i = tid; i < nW; i += stride) {
        float f[4];
        decode4(yfx[i], f);
        int c = (i & 7) * 4;
        f32x4 o;
        o[0] = fmaxf(f[0] * sc[c + 0] + bi[c + 0], 0.f);
        o[1] = fmaxf(f[1] * sc[c + 1] + bi[c + 1], 0.f);
        o[2] = fmaxf(f[2] * sc[c + 2] + bi[c + 2], 0.f);
        o[3] = fmaxf(f[3] * sc[c + 3] + bi[c + 3], 0.f);
        out4[i] = o;
    }
}

// =============================================================================

extern "C" void kernel_launch(void* const* d_in, const int* in_sizes, int n_in,
                              void* d_out, int out_size, void* d_ws, size_t ws_size,
                              hipStream_t stream)
{
    const float* x      = (const float*)d_in[0];
    const float* W      = (const float*)d_in[1];
    const float* gamma  = (const float*)d_in[2];
    const float* beta   = (const float*)d_in[3];
    const int*   in_idx = (const int*)d_in[4];
    const int*   out_idx= (const int*)d_in[5];

    const int P = in_sizes[4] / KOFF;
    const int N = in_sizes[0] / CH;
    const int n4 = out_size / 4;
    const int NB = (N + BINV - 1) / BINV;

    // ws layout: stats | cnt | pfx | binStart | binTot | cur | rec | xbf
    const size_t statsB = 1024;
    const size_t cntB   = (size_t)NBK * 4;
    const size_t pfxB   = (size_t)NBK * 4;
    const size_t bstB   = (size_t)NBINS * 4;
    const size_t btotB  = (size_t)NBINS * 4;
    const size_t curB   = (size_t)NBK * 4;
    const size_t recB   = (size_t)KOFF * P * 4;
    const size_t xbfB   = (size_t)N * CH * 2;
    const size_t needMid  = statsB + cntB + pfxB + bstB + btotB + curB + recB;
    const size_t needFull = needMid + xbfB;

    if (ws_size >= needMid) {
        const bool useXbf = (ws_size >= needFull);
        char* p = (char*)d_ws;
        float* stats  = (float*)p;            p += statsB;
        u32* cnt      = (u32*)p;              p += cntB;
        u32* pfx      = (u32*)p;              p += pfxB;
        u32* binStart = (u32*)p;              p += bstB;
        u32* binTot   = (u32*)p;              p += btotB;
        u32* cur      = (u32*)p;              p += curB;
        u32* rec      = (u32*)p;              p += recB;
        uint4* xbf    = (uint4*)p;

        hipMemsetAsync(d_ws, 0, statsB + cntB, stream);
        if (useXbf)
            xbf_kernel<<<2048, 256, 0, stream>>>(x, xbf, N * CH / 8);

        hist_kernel<<<2048, 256, 0, stream>>>(out_idx, cnt, P);
        binpfx_kernel<<<NBINS / 256, 256, 0, stream>>>(cnt, pfx, binTot);
        scan_kernel<<<1, 256, 0, stream>>>(binTot, binStart);
        initcur_kernel<<<(NBK + 255) / 256, 256, 0, stream>>>(binStart, pfx, cur);
        scatter_kernel<<<2048, 256, 0, stream>>>(in_idx, out_idx, cur, rec, P);

        if (useXbf)
            conv_bin_kernel<true><<<NB, 256, 0, stream>>>(
                xbf, x, W, rec, binStart, pfx, cur, stats, (float*)d_out, N);
        else
            conv_bin_kernel<false><<<NB, 256, 0, stream>>>(
                xbf, x, W, rec, binStart, pfx, cur, stats, (float*)d_out, N);

        bn_relu_kernel<<<2048, 256, 0, stream>>>(
            (f32x4*)d_out, stats, gamma, beta, 1.0f / (float)N, n4);
        return;
    }

    // -------- fallback: R2 u64 fixed-point atomic path --------
    const int tilesPerK = (P + 15) / 16;
    const int tilesPerWave = 8;
    const int blocksX = (tilesPerK + 4 * tilesPerWave - 1) / (4 * tilesPerWave);

    float* stats = (float*)d_ws;
    const size_t stB = 256;
    const size_t yfxBytes = (size_t)N * 8 * sizeof(u64);
    u64* yfx = (u64*)((char*)d_ws + stB);
    hipMemsetAsync(d_ws, 0, stB + yfxBytes, stream);

    conv_fx_kernel<<<dim3(blocksX, KOFF), 256, 0, stream>>>(
        x, W, in_idx, out_idx, yfx, P, tilesPerK, tilesPerWave);

    const int nW = N * 8;
    stats_fx_kernel<<<1024, 256, 0, stream>>>(yfx, stats, nW);
    bn_relu_fx_kernel<<<2048, 256, 0, stream>>>(yfx, (f32x4*)d_out, stats,
                                                gamma, beta, 1.0f / (float)N, nW);
}

// Round 7
// 1065.305 us; speedup vs baseline: 4.2996x; 4.2996x over previous
//
#include <hip/hip_runtime.h>

#define CH 32
#define KOFF 27
#define BN_EPS 1e-5f
#define FXS 512.0f          // fixed-point scale 2^9
#define FXI (1.0f / 512.0f)
#define TPW 8               // tiles per wave (unrolled)

typedef short bf16x8 __attribute__((ext_vector_type(8)));
typedef float f32x4 __attribute__((ext_vector_type(4)));
typedef unsigned long long u64;
typedef unsigned int u32;

__device__ __forceinline__ unsigned short f2bf(float f) {
    unsigned u = __builtin_bit_cast(unsigned, f);
    u = (u + 0x7fffu + ((u >> 16) & 1u)) >> 16;   // round-to-nearest-even
    return (unsigned short)u;
}

// Decode 4 sign-extended 16-bit field sums from an exact int64 accumulation.
__device__ __forceinline__ void decode4(u64 v, float* f) {
    long long w = (long long)v;
    int s0 = (short)(w & 0xFFFF);          w -= (long long)s0;
    int s1 = (short)((w >> 16) & 0xFFFF);  w -= ((long long)s1 << 16);
    int s2 = (short)((w >> 32) & 0xFFFF);  w -= ((long long)s2 << 32);
    int s3 = (int)(w >> 48);
    f[0] = s0 * FXI; f[1] = s1 * FXI; f[2] = s2 * FXI; f[3] = s3 * FXI;
}

// ---------------- fixed-point u64-atomic conv (pipelined) ----------------
// One wave = 16 rulebook pairs per tile, TPW tiles unrolled. B fragments
// column-permuted so lane r16 holds channels (2*r16, 2*r16+1); lane pairs
// exchange via shfl_xor to form 4-channel u64 addends; even lanes scatter
// D-rows {0,1}, odd lanes {2,3}: 2 u64 atomics/lane/tile.
// All in_idx/out_idx loads hoisted (affine addresses) so the per-tile
// dependent chain is gather -> MFMA -> quant -> atomic, pipelineable.
__global__ __launch_bounds__(256, 8) void conv_fx_kernel(
    const float* __restrict__ x, const float* __restrict__ W,
    const int* __restrict__ in_idx, const int* __restrict__ out_idx,
    u64* __restrict__ yfx,        // [N][8] u64: word m = channels 4m..4m+3
    int P, int tilesPerK)
{
    const int k    = blockIdx.y;
    const int lane = threadIdx.x & 63;
    const int wv   = threadIdx.x >> 6;
    const int r16  = lane & 15;
    const int g    = lane >> 4;

    const float* Wk = W + k * CH * CH;
    bf16x8 b0, b1;   // b0 -> channel 2*r16, b1 -> channel 2*r16+1
#pragma unroll
    for (int j = 0; j < 8; ++j) {
        int kk = g * 8 + j;
        b0[j] = (short)f2bf(Wk[kk * CH + 2 * r16]);
        b1[j] = (short)f2bf(Wk[kk * CH + 2 * r16 + 1]);
    }

    const int kP = k * P;
    const int t0 = (blockIdx.x * 4 + wv) * TPW;
    const int iBase = (r16 & 1) ? 2 : 0;   // D-rows this lane scatters
    const int m     = r16 >> 1;            // u64 column (channel quad)

    // Hoisted index loads (no dependencies -> all issue up front).
    int iiv[TPW], oi0[TPW], oi1[TPW];
#pragma unroll
    for (int u = 0; u < TPW; ++u) {
        const int base = (t0 + u) * 16;
        int pi = base + r16;         if (pi >= P) pi = P - 1;
        int p0 = base + g * 4 + iBase;
        int q0 = p0 < P ? p0 : P - 1;
        int q1 = p0 + 1 < P ? p0 + 1 : P - 1;
        iiv[u] = in_idx[kP + pi];
        oi0[u] = out_idx[kP + q0];
        oi1[u] = out_idx[kP + q1];
    }

#pragma unroll
    for (int u = 0; u < TPW; ++u) {
        const int base = (t0 + u) * 16;
        if (base >= tilesPerK * 16) break;

        const float* xr = x + (size_t)iiv[u] * CH + g * 8;
        f32x4 x0 = *(const f32x4*)xr;
        f32x4 x1 = *(const f32x4*)(xr + 4);
        bf16x8 a;
        a[0] = (short)f2bf(x0[0]); a[1] = (short)f2bf(x0[1]);
        a[2] = (short)f2bf(x0[2]); a[3] = (short)f2bf(x0[3]);
        a[4] = (short)f2bf(x1[0]); a[5] = (short)f2bf(x1[1]);
        a[6] = (short)f2bf(x1[2]); a[7] = (short)f2bf(x1[3]);

        f32x4 d0 = {0.f, 0.f, 0.f, 0.f};
        f32x4 d1 = {0.f, 0.f, 0.f, 0.f};
        d0 = __builtin_amdgcn_mfma_f32_16x16x32_bf16(a, b0, d0, 0, 0, 0);
        d1 = __builtin_amdgcn_mfma_f32_16x16x32_bf16(a, b1, d1, 0, 0, 0);

        // Quantize both channels per row, packed as 2x int16 in a u32.
        unsigned qi[4];
#pragma unroll
        for (int i = 0; i < 4; ++i) {
            int s0 = __float2int_rn(d0[i] * FXS);
            int s1 = __float2int_rn(d1[i] * FXS);
            qi[i] = (unsigned)(s0 & 0xFFFF) | ((unsigned)s1 << 16);
        }
        unsigned pq[4];
#pragma unroll
        for (int i = 0; i < 4; ++i) pq[i] = (unsigned)__shfl_xor((int)qi[i], 1);

        const int i0 = iBase, i1 = iBase + 1;
        {
            int a0 = (short)(qi[i0] & 0xFFFF), a1 = (short)(qi[i0] >> 16);
            int c0 = (short)(pq[i0] & 0xFFFF), c1 = (short)(pq[i0] >> 16);
            long long A = (!(r16 & 1))
                ? ((long long)a0 + ((long long)a1 << 16)
                 + ((long long)c0 << 32) + ((long long)c1 << 48))
                : ((long long)c0 + ((long long)c1 << 16)
                 + ((long long)a0 << 32) + ((long long)a1 << 48));
            if (base + g * 4 + i0 < P)
                atomicAdd(&yfx[(size_t)oi0[u] * 8 + m], (u64)A);
        }
        {
            int a0 = (short)(qi[i1] & 0xFFFF), a1 = (short)(qi[i1] >> 16);
            int c0 = (short)(pq[i1] & 0xFFFF), c1 = (short)(pq[i1] >> 16);
            long long A = (!(r16 & 1))
                ? ((long long)a0 + ((long long)a1 << 16)
                 + ((long long)c0 << 32) + ((long long)c1 << 48))
                : ((long long)c0 + ((long long)c1 << 16)
                 + ((long long)a0 << 32) + ((long long)a1 << 48));
            if (base + g * 4 + i1 < P)
                atomicAdd(&yfx[(size_t)oi1[u] * 8 + m], (u64)A);
        }
    }
}

__global__ __launch_bounds__(256) void stats_fx_kernel(
    const u64* __restrict__ yfx, float* __restrict__ stats, int nW)
{
    __shared__ float ls[CH], ls2[CH];
    if (threadIdx.x < CH) { ls[threadIdx.x] = 0.f; ls2[threadIdx.x] = 0.f; }
    __syncthreads();

    int tid = blockIdx.x * blockDim.x + threadIdx.x;
    int stride = gridDim.x * blockDim.x;   // multiple of 8 -> fixed quad per thread
    float s[4] = {0,0,0,0}, q[4] = {0,0,0,0};
    for (int i = tid; i < nW; i += stride) {
        float f[4];
        decode4(yfx[i], f);
#pragma unroll
        for (int j = 0; j < 4; ++j) { s[j] += f[j]; q[j] += f[j] * f[j]; }
    }
    int c = (tid & 7) * 4;
#pragma unroll
    for (int j = 0; j < 4; ++j) {
        atomicAdd(&ls[c + j], s[j]);
        atomicAdd(&ls2[c + j], q[j]);
    }
    __syncthreads();
    if (threadIdx.x < CH) {
        atomicAdd(&stats[threadIdx.x], ls[threadIdx.x]);
        atomicAdd(&stats[CH + threadIdx.x], ls2[threadIdx.x]);
    }
}

__global__ __launch_bounds__(256) void bn_relu_fx_kernel(
    const u64* __restrict__ yfx, f32x4* __restrict__ out4,
    const float* __restrict__ stats,
    const float* __restrict__ gamma, const float* __restrict__ beta,
    float invN, int nW)
{
    __shared__ float sc[CH], bi[CH];
    if (threadIdx.x < CH) {
        int c = threadIdx.x;
        float mean = stats[c] * invN;
        float var  = stats[CH + c] * invN - mean * mean;
        float s = gamma[c] * rsqrtf(var + BN_EPS);
        sc[c] = s;
        bi[c] = beta[c] - mean * s;
    }
    __syncthreads();

    int tid = blockIdx.x * blockDim.x + threadIdx.x;
    int stride = gridDim.x * blockDim.x;
    for (int i = tid; i < nW; i += stride) {
        float f[4];
        decode4(yfx[i], f);
        int c = (i & 7) * 4;
        f32x4 o;
        o[0] = fmaxf(f[0] * sc[c + 0] + bi[c + 0], 0.f);
        o[1] = fmaxf(f[1] * sc[c + 1] + bi[c + 1], 0.f);
        o[2] = fmaxf(f[2] * sc[c + 2] + bi[c + 2], 0.f);
        o[3] = fmaxf(f[3] * sc[c + 3] + bi[c + 3], 0.f);
        out4[i] = o;
    }
}

// ---------------- f32-atomic fallback (ws too small) ----------------
__global__ __launch_bounds__(256) void conv_kernel(
    const float* __restrict__ x, const float* __restrict__ W,
    const int* __restrict__ in_idx, const int* __restrict__ out_idx,
    float* __restrict__ y, int P, int tilesPerK, int tilesPerWave)
{
    const int k    = blockIdx.y;
    const int lane = threadIdx.x & 63;
    const int wv   = threadIdx.x >> 6;
    const int r16  = lane & 15;
    const int g    = lane >> 4;

    const float* Wk = W + k * CH * CH;
    bf16x8 b0, b1;
#pragma unroll
    for (int j = 0; j < 8; ++j) {
        int kk = g * 8 + j;
        b0[j] = (short)f2bf(Wk[kk * CH + r16]);
        b1[j] = (short)f2bf(Wk[kk * CH + 16 + r16]);
    }

    const int kP = k * P;
    int t0 = (blockIdx.x * 4 + wv) * tilesPerWave;
    int t1 = t0 + tilesPerWave;
    if (t1 > tilesPerK) t1 = tilesPerK;

    for (int t = t0; t < t1; ++t) {
        const int base = t * 16;
        int pi = base + r16;
        if (pi >= P) pi = P - 1;
        const int ii = in_idx[kP + pi];
        const float* xr = x + ii * CH + g * 8;
        f32x4 x0 = *(const f32x4*)xr;
        f32x4 x1 = *(const f32x4*)(xr + 4);
        bf16x8 a;
        a[0] = (short)f2bf(x0[0]); a[1] = (short)f2bf(x0[1]);
        a[2] = (short)f2bf(x0[2]); a[3] = (short)f2bf(x0[3]);
        a[4] = (short)f2bf(x1[0]); a[5] = (short)f2bf(x1[1]);
        a[6] = (short)f2bf(x1[2]); a[7] = (short)f2bf(x1[3]);

        f32x4 d0 = {0.f, 0.f, 0.f, 0.f};
        f32x4 d1 = {0.f, 0.f, 0.f, 0.f};
        d0 = __builtin_amdgcn_mfma_f32_16x16x32_bf16(a, b0, d0, 0, 0, 0);
        d1 = __builtin_amdgcn_mfma_f32_16x16x32_bf16(a, b1, d1, 0, 0, 0);

#pragma unroll
        for (int i = 0; i < 4; ++i) {
            int pr = base + g * 4 + i;
            if (pr < P) {
                int oi = out_idx[kP + pr];
                atomicAdd(&y[oi * CH + r16], d0[i]);
                atomicAdd(&y[oi * CH + 16 + r16], d1[i]);
            }
        }
    }
}

__global__ __launch_bounds__(256) void stats_kernel(
    const f32x4* __restrict__ y4, float* __restrict__ stats, int n4)
{
    __shared__ float ls[CH], ls2[CH];
    if (threadIdx.x < CH) { ls[threadIdx.x] = 0.f; ls2[threadIdx.x] = 0.f; }
    __syncthreads();

    int tid = blockIdx.x * blockDim.x + threadIdx.x;
    int stride = gridDim.x * blockDim.x;
    float s0 = 0, s1 = 0, s2 = 0, s3 = 0;
    float q0 = 0, q1 = 0, q2 = 0, q3 = 0;
    for (int i = tid; i < n4; i += stride) {
        f32x4 v = y4[i];
        s0 += v[0]; q0 += v[0] * v[0];
        s1 += v[1]; q1 += v[1] * v[1];
        s2 += v[2]; q2 += v[2] * v[2];
        s3 += v[3]; q3 += v[3] * v[3];
    }
    int c = (tid * 4) & (CH - 1);
    atomicAdd(&ls[c + 0], s0); atomicAdd(&ls[c + 1], s1);
    atomicAdd(&ls[c + 2], s2); atomicAdd(&ls[c + 3], s3);
    atomicAdd(&ls2[c + 0], q0); atomicAdd(&ls2[c + 1], q1);
    atomicAdd(&ls2[c + 2], q2); atomicAdd(&ls2[c + 3], q3);
    __syncthreads();
    if (threadIdx.x < CH) {
        atomicAdd(&stats[threadIdx.x], ls[threadIdx.x]);
        atomicAdd(&stats[CH + threadIdx.x], ls2[threadIdx.x]);
    }
}

__global__ __launch_bounds__(256) void bn_relu_kernel(
    f32x4* __restrict__ y4, const float* __restrict__ stats,
    const float* __restrict__ gamma, const float* __restrict__ beta,
    float invN, int n4)
{
    __shared__ float sc[CH], bi[CH];
    if (threadIdx.x < CH) {
        int c = threadIdx.x;
        float mean = stats[c] * invN;
        float var  = stats[CH + c] * invN - mean * mean;
        float s = gamma[c] * rsqrtf(var + BN_EPS);
        sc[c] = s;
        bi[c] = beta[c] - mean * s;
    }
    __syncthreads();

    int tid = blockIdx.x * blockDim.x + threadIdx.x;
    int stride = gridDim.x * blockDim.x;
    for (int i = tid; i < n4; i += stride) {
        f32x4 v = y4[i];
        int c = (i * 4) & (CH - 1);
        f32x4 o;
        o[0] = fmaxf(v[0] * sc[c + 0] + bi[c + 0], 0.f);
        o[1] = fmaxf(v[1] * sc[c + 1] + bi[c + 1], 0.f);
        o[2] = fmaxf(v[2] * sc[c + 2] + bi[c + 2], 0.f);
        o[3] = fmaxf(v[3] * sc[c + 3] + bi[c + 3], 0.f);
        y4[i] = o;
    }
}

extern "C" void kernel_launch(void* const* d_in, const int* in_sizes, int n_in,
                              void* d_out, int out_size, void* d_ws, size_t ws_size,
                              hipStream_t stream)
{
    const float* x      = (const float*)d_in[0];
    const float* W      = (const float*)d_in[1];
    const float* gamma  = (const float*)d_in[2];
    const float* beta   = (const float*)d_in[3];
    const int*   in_idx = (const int*)d_in[4];
    const int*   out_idx= (const int*)d_in[5];

    const int P = in_sizes[4] / KOFF;
    const int N = in_sizes[0] / CH;

    const int tilesPerK = (P + 15) / 16;

    float* stats = (float*)d_ws;
    const size_t statsBytes = 256;
    const size_t yfxBytes = (size_t)N * 8 * sizeof(u64);   // 64 MB

    if (ws_size >= statsBytes + yfxBytes) {
        u64* yfx = (u64*)((char*)d_ws + statsBytes);
        hipMemsetAsync(d_ws, 0, statsBytes + yfxBytes, stream);

        const int blocksX = (tilesPerK + 4 * TPW - 1) / (4 * TPW);
        conv_fx_kernel<<<dim3(blocksX, KOFF), 256, 0, stream>>>(
            x, W, in_idx, out_idx, yfx, P, tilesPerK);

        const int nW = N * 8;
        stats_fx_kernel<<<2048, 256, 0, stream>>>(yfx, stats, nW);
        bn_relu_fx_kernel<<<2048, 256, 0, stream>>>(yfx, (f32x4*)d_out, stats,
                                                    gamma, beta, 1.0f / (float)N, nW);
    } else {
        float* y = (float*)d_out;
        hipMemsetAsync(d_out, 0, (size_t)out_size * sizeof(float), stream);
        hipMemsetAsync(d_ws, 0, statsBytes, stream);

        const int tilesPerWave = 8;
        const int blocksX = (tilesPerK + 4 * tilesPerWave - 1) / (4 * tilesPerWave);
        conv_kernel<<<dim3(blocksX, KOFF), 256, 0, stream>>>(
            x, W, in_idx, out_idx, y, P, tilesPerK, tilesPerWave);

        const int n4 = out_size / 4;
        stats_kernel<<<1024, 256, 0, stream>>>((const f32x4*)d_out, stats, n4);
        bn_relu_kernel<<<2048, 256, 0, stream>>>((f32x4*)d_out, stats, gamma, beta,
                                                 1.0f / (float)N, n4);
    }
}

// Round 8
// 846.355 us; speedup vs baseline: 5.4119x; 1.2587x over previous
//
#include <hip/hip_runtime.h>

#define CH 32
#define KOFF 27
#define BN_EPS 1e-5f
#define FXS 512.0f          // fixed-point scale 2^9
#define FXI (1.0f / 512.0f)

typedef short bf16x8 __attribute__((ext_vector_type(8)));
typedef float f32x4 __attribute__((ext_vector_type(4)));
typedef unsigned long long u64;

__device__ __forceinline__ unsigned short f2bf(float f) {
    unsigned u = __builtin_bit_cast(unsigned, f);
    u = (u + 0x7fffu + ((u >> 16) & 1u)) >> 16;   // round-to-nearest-even
    return (unsigned short)u;
}

// Decode 4 sign-extended 16-bit field sums from an exact int64 accumulation.
__device__ __forceinline__ void decode4(u64 v, float* f) {
    long long w = (long long)v;
    int s0 = (short)(w & 0xFFFF);          w -= (long long)s0;
    int s1 = (short)((w >> 16) & 0xFFFF);  w -= ((long long)s1 << 16);
    int s2 = (short)((w >> 32) & 0xFFFF);  w -= ((long long)s2 << 32);
    int s3 = (int)(w >> 48);
    f[0] = s0 * FXI; f[1] = s1 * FXI; f[2] = s2 * FXI; f[3] = s3 * FXI;
}

// ---------------- fixed-point u64-atomic conv (R2 champion) ----------------
// One wave = 16 rulebook pairs. B fragments column-permuted so lane r16 holds
// channels (2*r16, 2*r16+1). Lane pairs (r16 even/odd) exchange via shfl_xor
// to assemble 4-channel 16-bit-field addends -> one u64 atomic covers 4 ch.
// Even lanes scatter D-rows {0,1}, odd lanes rows {2,3}: 2 atomics/lane/tile.
// NOTE (R6 lesson): do NOT hoist gathers/indices across tiles — 8-deep
// outstanding random 64B lines per wave thrashes L2 (FETCH +340MB, +30% time).
__global__ __launch_bounds__(256) void conv_fx_kernel(
    const float* __restrict__ x, const float* __restrict__ W,
    const int* __restrict__ in_idx, const int* __restrict__ out_idx,
    u64* __restrict__ yfx,        // [N][8] u64: word m = channels 4m..4m+3
    int P, int tilesPerK, int tilesPerWave)
{
    const int k    = blockIdx.y;
    const int lane = threadIdx.x & 63;
    const int wv   = threadIdx.x >> 6;
    const int r16  = lane & 15;
    const int g    = lane >> 4;

    const float* Wk = W + k * CH * CH;
    bf16x8 b0, b1;   // b0 -> channel 2*r16, b1 -> channel 2*r16+1
#pragma unroll
    for (int j = 0; j < 8; ++j) {
        int kk = g * 8 + j;
        b0[j] = (short)f2bf(Wk[kk * CH + 2 * r16]);
        b1[j] = (short)f2bf(Wk[kk * CH + 2 * r16 + 1]);
    }

    const int kP = k * P;
    int t0 = (blockIdx.x * 4 + wv) * tilesPerWave;
    int t1 = t0 + tilesPerWave;
    if (t1 > tilesPerK) t1 = tilesPerK;

    const int iBase = (r16 & 1) ? 2 : 0;
    const int m     = r16 >> 1;

    for (int t = t0; t < t1; ++t) {
        const int base = t * 16;
        int pi = base + r16;
        if (pi >= P) pi = P - 1;
        const int ii = in_idx[kP + pi];
        const float* xr = x + ii * CH + g * 8;
        f32x4 x0 = *(const f32x4*)xr;
        f32x4 x1 = *(const f32x4*)(xr + 4);
        bf16x8 a;
        a[0] = (short)f2bf(x0[0]); a[1] = (short)f2bf(x0[1]);
        a[2] = (short)f2bf(x0[2]); a[3] = (short)f2bf(x0[3]);
        a[4] = (short)f2bf(x1[0]); a[5] = (short)f2bf(x1[1]);
        a[6] = (short)f2bf(x1[2]); a[7] = (short)f2bf(x1[3]);

        f32x4 d0 = {0.f, 0.f, 0.f, 0.f};
        f32x4 d1 = {0.f, 0.f, 0.f, 0.f};
        d0 = __builtin_amdgcn_mfma_f32_16x16x32_bf16(a, b0, d0, 0, 0, 0);
        d1 = __builtin_amdgcn_mfma_f32_16x16x32_bf16(a, b1, d1, 0, 0, 0);

        unsigned qi[4];
#pragma unroll
        for (int i = 0; i < 4; ++i) {
            int s0 = __float2int_rn(d0[i] * FXS);
            int s1 = __float2int_rn(d1[i] * FXS);
            qi[i] = (unsigned)(s0 & 0xFFFF) | ((unsigned)s1 << 16);
        }
        unsigned pq[4];
#pragma unroll
        for (int i = 0; i < 4; ++i) pq[i] = (unsigned)__shfl_xor((int)qi[i], 1);

#pragma unroll
        for (int s = 0; s < 2; ++s) {
            const int i  = iBase + s;
            const int pr = base + g * 4 + i;
            if (pr < P) {
                const int oi = out_idx[kP + pr];
                int a0 = (short)(qi[i] & 0xFFFF), a1 = (short)(qi[i] >> 16);
                int c0 = (short)(pq[i] & 0xFFFF), c1 = (short)(pq[i] >> 16);
                long long A;
                if (!(r16 & 1))
                    A = (long long)a0 + ((long long)a1 << 16)
                      + ((long long)c0 << 32) + ((long long)c1 << 48);
                else
                    A = (long long)c0 + ((long long)c1 << 16)
                      + ((long long)a0 << 32) + ((long long)a1 << 48);
                atomicAdd(&yfx[(size_t)oi * 8 + m], (u64)A);
            }
        }
    }
}

__global__ __launch_bounds__(256) void stats_fx_kernel(
    const u64* __restrict__ yfx, float* __restrict__ stats, int nW)
{
    __shared__ float ls[CH], ls2[CH];
    if (threadIdx.x < CH) { ls[threadIdx.x] = 0.f; ls2[threadIdx.x] = 0.f; }
    __syncthreads();

    int tid = blockIdx.x * blockDim.x + threadIdx.x;
    int stride = gridDim.x * blockDim.x;   // multiple of 8 -> fixed quad per thread
    float s[4] = {0,0,0,0}, q[4] = {0,0,0,0};
    for (int i = tid; i < nW; i += stride) {
        float f[4];
        decode4(yfx[i], f);
#pragma unroll
        for (int j = 0; j < 4; ++j) { s[j] += f[j]; q[j] += f[j] * f[j]; }
    }
    int c = (tid & 7) * 4;
#pragma unroll
    for (int j = 0; j < 4; ++j) {
        atomicAdd(&ls[c + j], s[j]);
        atomicAdd(&ls2[c + j], q[j]);
    }
    __syncthreads();
    if (threadIdx.x < CH) {
        atomicAdd(&stats[threadIdx.x], ls[threadIdx.x]);
        atomicAdd(&stats[CH + threadIdx.x], ls2[threadIdx.x]);
    }
}

__global__ __launch_bounds__(256) void bn_relu_fx_kernel(
    const u64* __restrict__ yfx, f32x4* __restrict__ out4,
    const float* __restrict__ stats,
    const float* __restrict__ gamma, const float* __restrict__ beta,
    float invN, int nW)
{
    __shared__ float sc[CH], bi[CH];
    if (threadIdx.x < CH) {
        int c = threadIdx.x;
        float mean = stats[c] * invN;
        float var  = stats[CH + c] * invN - mean * mean;
        float s = gamma[c] * rsqrtf(var + BN_EPS);
        sc[c] = s;
        bi[c] = beta[c] - mean * s;
    }
    __syncthreads();

    int tid = blockIdx.x * blockDim.x + threadIdx.x;
    int stride = gridDim.x * blockDim.x;
    for (int i = tid; i < nW; i += stride) {
        float f[4];
        decode4(yfx[i], f);
        int c = (i & 7) * 4;
        f32x4 o;
        o[0] = fmaxf(f[0] * sc[c + 0] + bi[c + 0], 0.f);
        o[1] = fmaxf(f[1] * sc[c + 1] + bi[c + 1], 0.f);
        o[2] = fmaxf(f[2] * sc[c + 2] + bi[c + 2], 0.f);
        o[3] = fmaxf(f[3] * sc[c + 3] + bi[c + 3], 0.f);
        out4[i] = o;
    }
}

// ---------------- f32-atomic fallback (ws too small) ----------------
__global__ __launch_bounds__(256) void conv_kernel(
    const float* __restrict__ x, const float* __restrict__ W,
    const int* __restrict__ in_idx, const int* __restrict__ out_idx,
    float* __restrict__ y, int P, int tilesPerK, int tilesPerWave)
{
    const int k    = blockIdx.y;
    const int lane = threadIdx.x & 63;
    const int wv   = threadIdx.x >> 6;
    const int r16  = lane & 15;
    const int g    = lane >> 4;

    const float* Wk = W + k * CH * CH;
    bf16x8 b0, b1;
#pragma unroll
    for (int j = 0; j < 8; ++j) {
        int kk = g * 8 + j;
        b0[j] = (short)f2bf(Wk[kk * CH + r16]);
        b1[j] = (short)f2bf(Wk[kk * CH + 16 + r16]);
    }

    const int kP = k * P;
    int t0 = (blockIdx.x * 4 + wv) * tilesPerWave;
    int t1 = t0 + tilesPerWave;
    if (t1 > tilesPerK) t1 = tilesPerK;

    for (int t = t0; t < t1; ++t) {
        const int base = t * 16;
        int pi = base + r16;
        if (pi >= P) pi = P - 1;
        const int ii = in_idx[kP + pi];
        const float* xr = x + ii * CH + g * 8;
        f32x4 x0 = *(const f32x4*)xr;
        f32x4 x1 = *(const f32x4*)(xr + 4);
        bf16x8 a;
        a[0] = (short)f2bf(x0[0]); a[1] = (short)f2bf(x0[1]);
        a[2] = (short)f2bf(x0[2]); a[3] = (short)f2bf(x0[3]);
        a[4] = (short)f2bf(x1[0]); a[5] = (short)f2bf(x1[1]);
        a[6] = (short)f2bf(x1[2]); a[7] = (short)f2bf(x1[3]);

        f32x4 d0 = {0.f, 0.f, 0.f, 0.f};
        f32x4 d1 = {0.f, 0.f, 0.f, 0.f};
        d0 = __builtin_amdgcn_mfma_f32_16x16x32_bf16(a, b0, d0, 0, 0, 0);
        d1 = __builtin_amdgcn_mfma_f32_16x16x32_bf16(a, b1, d1, 0, 0, 0);

#pragma unroll
        for (int i = 0; i < 4; ++i) {
            int pr = base + g * 4 + i;
            if (pr < P) {
                int oi = out_idx[kP + pr];
                atomicAdd(&y[oi * CH + r16], d0[i]);
                atomicAdd(&y[oi * CH + 16 + r16], d1[i]);
            }
        }
    }
}

__global__ __launch_bounds__(256) void stats_kernel(
    const f32x4* __restrict__ y4, float* __restrict__ stats, int n4)
{
    __shared__ float ls[CH], ls2[CH];
    if (threadIdx.x < CH) { ls[threadIdx.x] = 0.f; ls2[threadIdx.x] = 0.f; }
    __syncthreads();

    int tid = blockIdx.x * blockDim.x + threadIdx.x;
    int stride = gridDim.x * blockDim.x;
    float s0 = 0, s1 = 0, s2 = 0, s3 = 0;
    float q0 = 0, q1 = 0, q2 = 0, q3 = 0;
    for (int i = tid; i < n4; i += stride) {
        f32x4 v = y4[i];
        s0 += v[0]; q0 += v[0] * v[0];
        s1 += v[1]; q1 += v[1] * v[1];
        s2 += v[2]; q2 += v[2] * v[2];
        s3 += v[3]; q3 += v[3] * v[3];
    }
    int c = (tid * 4) & (CH - 1);
    atomicAdd(&ls[c + 0], s0); atomicAdd(&ls[c + 1], s1);
    atomicAdd(&ls[c + 2], s2); atomicAdd(&ls[c + 3], s3);
    atomicAdd(&ls2[c + 0], q0); atomicAdd(&ls2[c + 1], q1);
    atomicAdd(&ls2[c + 2], q2); atomicAdd(&ls2[c + 3], q3);
    __syncthreads();
    if (threadIdx.x < CH) {
        atomicAdd(&stats[threadIdx.x], ls[threadIdx.x]);
        atomicAdd(&stats[CH + threadIdx.x], ls2[threadIdx.x]);
    }
}

__global__ __launch_bounds__(256) void bn_relu_kernel(
    f32x4* __restrict__ y4, const float* __restrict__ stats,
    const float* __restrict__ gamma, const float* __restrict__ beta,
    float invN, int n4)
{
    __shared__ float sc[CH], bi[CH];
    if (threadIdx.x < CH) {
        int c = threadIdx.x;
        float mean = stats[c] * invN;
        float var  = stats[CH + c] * invN - mean * mean;
        float s = gamma[c] * rsqrtf(var + BN_EPS);
        sc[c] = s;
        bi[c] = beta[c] - mean * s;
    }
    __syncthreads();

    int tid = blockIdx.x * blockDim.x + threadIdx.x;
    int stride = gridDim.x * blockDim.x;
    for (int i = tid; i < n4; i += stride) {
        f32x4 v = y4[i];
        int c = (i * 4) & (CH - 1);
        f32x4 o;
        o[0] = fmaxf(v[0] * sc[c + 0] + bi[c + 0], 0.f);
        o[1] = fmaxf(v[1] * sc[c + 1] + bi[c + 1], 0.f);
        o[2] = fmaxf(v[2] * sc[c + 2] + bi[c + 2], 0.f);
        o[3] = fmaxf(v[3] * sc[c + 3] + bi[c + 3], 0.f);
        y4[i] = o;
    }
}

extern "C" void kernel_launch(void* const* d_in, const int* in_sizes, int n_in,
                              void* d_out, int out_size, void* d_ws, size_t ws_size,
                              hipStream_t stream)
{
    const float* x      = (const float*)d_in[0];
    const float* W      = (const float*)d_in[1];
    const float* gamma  = (const float*)d_in[2];
    const float* beta   = (const float*)d_in[3];
    const int*   in_idx = (const int*)d_in[4];
    const int*   out_idx= (const int*)d_in[5];

    const int P = in_sizes[4] / KOFF;
    const int N = in_sizes[0] / CH;

    const int tilesPerK = (P + 15) / 16;
    const int tilesPerWave = 8;
    const int blocksX = (tilesPerK + 4 * tilesPerWave - 1) / (4 * tilesPerWave);

    float* stats = (float*)d_ws;
    const size_t statsBytes = 256;
    const size_t yfxBytes = (size_t)N * 8 * sizeof(u64);   // 64 MB

    if (ws_size >= statsBytes + yfxBytes) {
        u64* yfx = (u64*)((char*)d_ws + statsBytes);
        hipMemsetAsync(d_ws, 0, statsBytes + yfxBytes, stream);

        conv_fx_kernel<<<dim3(blocksX, KOFF), 256, 0, stream>>>(
            x, W, in_idx, out_idx, yfx, P, tilesPerK, tilesPerWave);

        const int nW = N * 8;
        stats_fx_kernel<<<2048, 256, 0, stream>>>(yfx, stats, nW);
        bn_relu_fx_kernel<<<2048, 256, 0, stream>>>(yfx, (f32x4*)d_out, stats,
                                                    gamma, beta, 1.0f / (float)N, nW);
    } else {
        float* y = (float*)d_out;
        hipMemsetAsync(d_out, 0, (size_t)out_size * sizeof(float), stream);
        hipMemsetAsync(d_ws, 0, statsBytes, stream);

        conv_kernel<<<dim3(blocksX, KOFF), 256, 0, stream>>>(
            x, W, in_idx, out_idx, y, P, tilesPerK, tilesPerWave);

        const int n4 = out_size / 4;
        stats_kernel<<<1024, 256, 0, stream>>>((const f32x4*)d_out, stats, n4);
        bn_relu_kernel<<<2048, 256, 0, stream>>>((f32x4*)d_out, stats, gamma, beta,
                                                 1.0f / (float)N, n4);
    }
}

// Round 9
// 840.186 us; speedup vs baseline: 5.4517x; 1.0073x over previous
//
#include <hip/hip_runtime.h>

#define CH 32
#define KOFF 27
#define BN_EPS 1e-5f
#define FXS 512.0f          // fixed-point scale 2^9
#define FXI (1.0f / 512.0f)
#define TPW 8               // tiles per wave

typedef short bf16x8 __attribute__((ext_vector_type(8)));
typedef float f32x4 __attribute__((ext_vector_type(4)));
typedef unsigned long long u64;

__device__ __forceinline__ unsigned short f2bf(float f) {
    unsigned u = __builtin_bit_cast(unsigned, f);
    u = (u + 0x7fffu + ((u >> 16) & 1u)) >> 16;   // round-to-nearest-even
    return (unsigned short)u;
}

// Decode 4 sign-extended 16-bit field sums from an exact int64 accumulation.
__device__ __forceinline__ void decode4(u64 v, float* f) {
    long long w = (long long)v;
    int s0 = (short)(w & 0xFFFF);          w -= (long long)s0;
    int s1 = (short)((w >> 16) & 0xFFFF);  w -= ((long long)s1 << 16);
    int s2 = (short)((w >> 32) & 0xFFFF);  w -= ((long long)s2 << 32);
    int s3 = (int)(w >> 48);
    f[0] = s0 * FXI; f[1] = s1 * FXI; f[2] = s2 * FXI; f[3] = s3 * FXI;
}

// ---------------- fixed-point u64-atomic conv (depth-1 gather pipeline) -----
// R2 structure; changes vs R2:
//  * idx loads for all TPW tiles hoisted (COALESCED sequential lines — cheap;
//    R6's mistake was hoisting the RANDOM gathers 8 deep, which thrashed L2)
//  * x-gather prefetched 1 tile ahead (2 random lines in flight per wave)
__global__ __launch_bounds__(256) void conv_fx_kernel(
    const float* __restrict__ x, const float* __restrict__ W,
    const int* __restrict__ in_idx, const int* __restrict__ out_idx,
    u64* __restrict__ yfx,        // [N][8] u64: word m = channels 4m..4m+3
    int P, int tilesPerK)
{
    const int k    = blockIdx.y;
    const int lane = threadIdx.x & 63;
    const int wv   = threadIdx.x >> 6;
    const int r16  = lane & 15;
    const int g    = lane >> 4;

    const float* Wk = W + k * CH * CH;
    bf16x8 b0, b1;   // b0 -> channel 2*r16, b1 -> channel 2*r16+1
#pragma unroll
    for (int j = 0; j < 8; ++j) {
        int kk = g * 8 + j;
        b0[j] = (short)f2bf(Wk[kk * CH + 2 * r16]);
        b1[j] = (short)f2bf(Wk[kk * CH + 2 * r16 + 1]);
    }

    const int kP = k * P;
    const int t0 = (blockIdx.x * 4 + wv) * TPW;
    if (t0 >= tilesPerK) return;
    const int nt = min(TPW, tilesPerK - t0);

    const int iBase = (r16 & 1) ? 2 : 0;   // D-rows this lane scatters
    const int m     = r16 >> 1;            // u64 column (channel quad)

    // Hoisted idx loads — sequential/coalesced addresses, safe to batch.
    int iiv[TPW], oiA[TPW], oiB[TPW];
#pragma unroll
    for (int u = 0; u < TPW; ++u) {
        const int base = (t0 + u) * 16;
        int pi = base + r16;         if (pi >= P) pi = P - 1;
        int p0 = base + g * 4 + iBase;
        int q0 = p0 < P ? p0 : P - 1;
        int q1 = p0 + 1 < P ? p0 + 1 : P - 1;
        iiv[u] = in_idx[kP + pi];
        oiA[u] = out_idx[kP + q0];
        oiB[u] = out_idx[kP + q1];
    }

    // Depth-1 gather pipeline.
    const float* xr0 = x + (size_t)iiv[0] * CH + g * 8;
    f32x4 cx0 = *(const f32x4*)xr0;
    f32x4 cx1 = *(const f32x4*)(xr0 + 4);

#pragma unroll
    for (int u = 0; u < TPW; ++u) {
        if (u >= nt) break;

        f32x4 nx0, nx1;
        if (u + 1 < TPW) {                 // prefetch next tile's gather
            const float* nxr = x + (size_t)iiv[u + 1] * CH + g * 8;
            nx0 = *(const f32x4*)nxr;
            nx1 = *(const f32x4*)(nxr + 4);
        }

        bf16x8 a;
        a[0] = (short)f2bf(cx0[0]); a[1] = (short)f2bf(cx0[1]);
        a[2] = (short)f2bf(cx0[2]); a[3] = (short)f2bf(cx0[3]);
        a[4] = (short)f2bf(cx1[0]); a[5] = (short)f2bf(cx1[1]);
        a[6] = (short)f2bf(cx1[2]); a[7] = (short)f2bf(cx1[3]);

        f32x4 d0 = {0.f, 0.f, 0.f, 0.f};
        f32x4 d1 = {0.f, 0.f, 0.f, 0.f};
        d0 = __builtin_amdgcn_mfma_f32_16x16x32_bf16(a, b0, d0, 0, 0, 0);
        d1 = __builtin_amdgcn_mfma_f32_16x16x32_bf16(a, b1, d1, 0, 0, 0);

        unsigned qi[4];
#pragma unroll
        for (int i = 0; i < 4; ++i) {
            int s0 = __float2int_rn(d0[i] * FXS);
            int s1 = __float2int_rn(d1[i] * FXS);
            qi[i] = (unsigned)(s0 & 0xFFFF) | ((unsigned)s1 << 16);
        }
        unsigned pq[4];
#pragma unroll
        for (int i = 0; i < 4; ++i) pq[i] = (unsigned)__shfl_xor((int)qi[i], 1);

        const int base = (t0 + u) * 16;
        const int i0 = iBase, i1 = iBase + 1;
        {
            int a0 = (short)(qi[i0] & 0xFFFF), a1 = (short)(qi[i0] >> 16);
            int c0 = (short)(pq[i0] & 0xFFFF), c1 = (short)(pq[i0] >> 16);
            long long A = (!(r16 & 1))
                ? ((long long)a0 + ((long long)a1 << 16)
                 + ((long long)c0 << 32) + ((long long)c1 << 48))
                : ((long long)c0 + ((long long)c1 << 16)
                 + ((long long)a0 << 32) + ((long long)a1 << 48));
            if (base + g * 4 + i0 < P)
                atomicAdd(&yfx[(size_t)oiA[u] * 8 + m], (u64)A);
        }
        {
            int a0 = (short)(qi[i1] & 0xFFFF), a1 = (short)(qi[i1] >> 16);
            int c0 = (short)(pq[i1] & 0xFFFF), c1 = (short)(pq[i1] >> 16);
            long long A = (!(r16 & 1))
                ? ((long long)a0 + ((long long)a1 << 16)
                 + ((long long)c0 << 32) + ((long long)c1 << 48))
                : ((long long)c0 + ((long long)c1 << 16)
                 + ((long long)a0 << 32) + ((long long)a1 << 48));
            if (base + g * 4 + i1 < P)
                atomicAdd(&yfx[(size_t)oiB[u] * 8 + m], (u64)A);
        }

        cx0 = nx0; cx1 = nx1;
    }
}

__global__ __launch_bounds__(256) void stats_fx_kernel(
    const u64* __restrict__ yfx, float* __restrict__ stats, int nW)
{
    __shared__ float ls[CH], ls2[CH];
    if (threadIdx.x < CH) { ls[threadIdx.x] = 0.f; ls2[threadIdx.x] = 0.f; }
    __syncthreads();

    int tid = blockIdx.x * blockDim.x + threadIdx.x;
    int stride = gridDim.x * blockDim.x;   // multiple of 8 -> fixed quad per thread
    float s[4] = {0,0,0,0}, q[4] = {0,0,0,0};
    for (int i = tid; i < nW; i += stride) {
        float f[4];
        decode4(yfx[i], f);
#pragma unroll
        for (int j = 0; j < 4; ++j) { s[j] += f[j]; q[j] += f[j] * f[j]; }
    }
    int c = (tid & 7) * 4;
#pragma unroll
    for (int j = 0; j < 4; ++j) {
        atomicAdd(&ls[c + j], s[j]);
        atomicAdd(&ls2[c + j], q[j]);
    }
    __syncthreads();
    if (threadIdx.x < CH) {
        atomicAdd(&stats[threadIdx.x], ls[threadIdx.x]);
        atomicAdd(&stats[CH + threadIdx.x], ls2[threadIdx.x]);
    }
}

__global__ __launch_bounds__(256) void bn_relu_fx_kernel(
    const u64* __restrict__ yfx, f32x4* __restrict__ out4,
    const float* __restrict__ stats,
    const float* __restrict__ gamma, const float* __restrict__ beta,
    float invN, int nW)
{
    __shared__ float sc[CH], bi[CH];
    if (threadIdx.x < CH) {
        int c = threadIdx.x;
        float mean = stats[c] * invN;
        float var  = stats[CH + c] * invN - mean * mean;
        float s = gamma[c] * rsqrtf(var + BN_EPS);
        sc[c] = s;
        bi[c] = beta[c] - mean * s;
    }
    __syncthreads();

    int tid = blockIdx.x * blockDim.x + threadIdx.x;
    int stride = gridDim.x * blockDim.x;
    for (int i = tid; i < nW; i += stride) {
        float f[4];
        decode4(yfx[i], f);
        int c = (i & 7) * 4;
        f32x4 o;
        o[0] = fmaxf(f[0] * sc[c + 0] + bi[c + 0], 0.f);
        o[1] = fmaxf(f[1] * sc[c + 1] + bi[c + 1], 0.f);
        o[2] = fmaxf(f[2] * sc[c + 2] + bi[c + 2], 0.f);
        o[3] = fmaxf(f[3] * sc[c + 3] + bi[c + 3], 0.f);
        out4[i] = o;
    }
}

// ---------------- f32-atomic fallback (ws too small) ----------------
__global__ __launch_bounds__(256) void conv_kernel(
    const float* __restrict__ x, const float* __restrict__ W,
    const int* __restrict__ in_idx, const int* __restrict__ out_idx,
    float* __restrict__ y, int P, int tilesPerK, int tilesPerWave)
{
    const int k    = blockIdx.y;
    const int lane = threadIdx.x & 63;
    const int wv   = threadIdx.x >> 6;
    const int r16  = lane & 15;
    const int g    = lane >> 4;

    const float* Wk = W + k * CH * CH;
    bf16x8 b0, b1;
#pragma unroll
    for (int j = 0; j < 8; ++j) {
        int kk = g * 8 + j;
        b0[j] = (short)f2bf(Wk[kk * CH + r16]);
        b1[j] = (short)f2bf(Wk[kk * CH + 16 + r16]);
    }

    const int kP = k * P;
    int t0 = (blockIdx.x * 4 + wv) * tilesPerWave;
    int t1 = t0 + tilesPerWave;
    if (t1 > tilesPerK) t1 = tilesPerK;

    for (int t = t0; t < t1; ++t) {
        const int base = t * 16;
        int pi = base + r16;
        if (pi >= P) pi = P - 1;
        const int ii = in_idx[kP + pi];
        const float* xr = x + ii * CH + g * 8;
        f32x4 x0 = *(const f32x4*)xr;
        f32x4 x1 = *(const f32x4*)(xr + 4);
        bf16x8 a;
        a[0] = (short)f2bf(x0[0]); a[1] = (short)f2bf(x0[1]);
        a[2] = (short)f2bf(x0[2]); a[3] = (short)f2bf(x0[3]);
        a[4] = (short)f2bf(x1[0]); a[5] = (short)f2bf(x1[1]);
        a[6] = (short)f2bf(x1[2]); a[7] = (short)f2bf(x1[3]);

        f32x4 d0 = {0.f, 0.f, 0.f, 0.f};
        f32x4 d1 = {0.f, 0.f, 0.f, 0.f};
        d0 = __builtin_amdgcn_mfma_f32_16x16x32_bf16(a, b0, d0, 0, 0, 0);
        d1 = __builtin_amdgcn_mfma_f32_16x16x32_bf16(a, b1, d1, 0, 0, 0);

#pragma unroll
        for (int i = 0; i < 4; ++i) {
            int pr = base + g * 4 + i;
            if (pr < P) {
                int oi = out_idx[kP + pr];
                atomicAdd(&y[oi * CH + r16], d0[i]);
                atomicAdd(&y[oi * CH + 16 + r16], d1[i]);
            }
        }
    }
}

__global__ __launch_bounds__(256) void stats_kernel(
    const f32x4* __restrict__ y4, float* __restrict__ stats, int n4)
{
    __shared__ float ls[CH], ls2[CH];
    if (threadIdx.x < CH) { ls[threadIdx.x] = 0.f; ls2[threadIdx.x] = 0.f; }
    __syncthreads();

    int tid = blockIdx.x * blockDim.x + threadIdx.x;
    int stride = gridDim.x * blockDim.x;
    float s0 = 0, s1 = 0, s2 = 0, s3 = 0;
    float q0 = 0, q1 = 0, q2 = 0, q3 = 0;
    for (int i = tid; i < n4; i += stride) {
        f32x4 v = y4[i];
        s0 += v[0]; q0 += v[0] * v[0];
        s1 += v[1]; q1 += v[1] * v[1];
        s2 += v[2]; q2 += v[2] * v[2];
        s3 += v[3]; q3 += v[3] * v[3];
    }
    int c = (tid * 4) & (CH - 1);
    atomicAdd(&ls[c + 0], s0); atomicAdd(&ls[c + 1], s1);
    atomicAdd(&ls[c + 2], s2); atomicAdd(&ls[c + 3], s3);
    atomicAdd(&ls2[c + 0], q0); atomicAdd(&ls2[c + 1], q1);
    atomicAdd(&ls2[c + 2], q2); atomicAdd(&ls2[c + 3], q3);
    __syncthreads();
    if (threadIdx.x < CH) {
        atomicAdd(&stats[threadIdx.x], ls[threadIdx.x]);
        atomicAdd(&stats[CH + threadIdx.x], ls2[threadIdx.x]);
    }
}

__global__ __launch_bounds__(256) void bn_relu_kernel(
    f32x4* __restrict__ y4, const float* __restrict__ stats,
    const float* __restrict__ gamma, const float* __restrict__ beta,
    float invN, int n4)
{
    __shared__ float sc[CH], bi[CH];
    if (threadIdx.x < CH) {
        int c = threadIdx.x;
        float mean = stats[c] * invN;
        float var  = stats[CH + c] * invN - mean * mean;
        float s = gamma[c] * rsqrtf(var + BN_EPS);
        sc[c] = s;
        bi[c] = beta[c] - mean * s;
    }
    __syncthreads();

    int tid = blockIdx.x * blockDim.x + threadIdx.x;
    int stride = gridDim.x * blockDim.x;
    for (int i = tid; i < n4; i += stride) {
        f32x4 v = y4[i];
        int c = (i * 4) & (CH - 1);
        f32x4 o;
        o[0] = fmaxf(v[0] * sc[c + 0] + bi[c + 0], 0.f);
        o[1] = fmaxf(v[1] * sc[c + 1] + bi[c + 1], 0.f);
        o[2] = fmaxf(v[2] * sc[c + 2] + bi[c + 2], 0.f);
        o[3] = fmaxf(v[3] * sc[c + 3] + bi[c + 3], 0.f);
        y4[i] = o;
    }
}

extern "C" void kernel_launch(void* const* d_in, const int* in_sizes, int n_in,
                              void* d_out, int out_size, void* d_ws, size_t ws_size,
                              hipStream_t stream)
{
    const float* x      = (const float*)d_in[0];
    const float* W      = (const float*)d_in[1];
    const float* gamma  = (const float*)d_in[2];
    const float* beta   = (const float*)d_in[3];
    const int*   in_idx = (const int*)d_in[4];
    const int*   out_idx= (const int*)d_in[5];

    const int P = in_sizes[4] / KOFF;
    const int N = in_sizes[0] / CH;

    const int tilesPerK = (P + 15) / 16;
    const int blocksX = (tilesPerK + 4 * TPW - 1) / (4 * TPW);

    float* stats = (float*)d_ws;
    const size_t statsBytes = 256;
    const size_t yfxBytes = (size_t)N * 8 * sizeof(u64);   // 64 MB

    if (ws_size >= statsBytes + yfxBytes) {
        u64* yfx = (u64*)((char*)d_ws + statsBytes);
        hipMemsetAsync(d_ws, 0, statsBytes + yfxBytes, stream);

        conv_fx_kernel<<<dim3(blocksX, KOFF), 256, 0, stream>>>(
            x, W, in_idx, out_idx, yfx, P, tilesPerK);

        const int nW = N * 8;
        stats_fx_kernel<<<2048, 256, 0, stream>>>(yfx, stats, nW);
        bn_relu_fx_kernel<<<2048, 256, 0, stream>>>(yfx, (f32x4*)d_out, stats,
                                                    gamma, beta, 1.0f / (float)N, nW);
    } else {
        float* y = (float*)d_out;
        hipMemsetAsync(d_out, 0, (size_t)out_size * sizeof(float), stream);
        hipMemsetAsync(d_ws, 0, statsBytes, stream);

        conv_kernel<<<dim3(blocksX, KOFF), 256, 0, stream>>>(
            x, W, in_idx, out_idx, y, P, tilesPerK, TPW);

        const int n4 = out_size / 4;
        stats_kernel<<<1024, 256, 0, stream>>>((const f32x4*)d_out, stats, n4);
        bn_relu_kernel<<<2048, 256, 0, stream>>>((f32x4*)d_out, stats, gamma, beta,
                                                 1.0f / (float)N, n4);
    }
}